// Round 6
// baseline (28.740 us; speedup 1.0000x reference)
//
#include <hip/hip_runtime.h>
#include <algorithm>
#include <cstdint>

// ---------------------------------------------------------------------------
// Host-side reproduction of jax.random.permutation(jax.random.key(42), 128)
// under jax_threefry_partitionable=True (default since JAX 0.4.36):
//   subkey = threefry_block(key=(0,42), x0=0, x1=1) (both output words)
//   bits[i] = x0out ^ x1out of block(subkey, x0=0, x1=i), i in [0,128)
//   perm = stable argsort(bits); use perm[0:25]
// (Verified passing on this harness, rounds 2-5.)
// ---------------------------------------------------------------------------

static inline void threefry2x32_block(uint32_t k0, uint32_t k1,
                                      uint32_t& x0, uint32_t& x1) {
  auto rotl = [](uint32_t v, int d) { return (v << d) | (v >> (32 - d)); };
  const int r0[4] = {13, 15, 26, 6};
  const int r1[4] = {17, 29, 16, 24};
  const uint32_t ks0 = k0, ks1 = k1, ks2 = k0 ^ k1 ^ 0x1BD11BDAu;
  x0 += ks0; x1 += ks1;
  for (int i = 0; i < 4; ++i) { x0 += x1; x1 = rotl(x1, r0[i]); x1 ^= x0; }
  x0 += ks1; x1 += ks2 + 1u;
  for (int i = 0; i < 4; ++i) { x0 += x1; x1 = rotl(x1, r1[i]); x1 ^= x0; }
  x0 += ks2; x1 += ks0 + 2u;
  for (int i = 0; i < 4; ++i) { x0 += x1; x1 = rotl(x1, r0[i]); x1 ^= x0; }
  x0 += ks0; x1 += ks1 + 3u;
  for (int i = 0; i < 4; ++i) { x0 += x1; x1 = rotl(x1, r1[i]); x1 ^= x0; }
  x0 += ks1; x1 += ks2 + 4u;
  for (int i = 0; i < 4; ++i) { x0 += x1; x1 = rotl(x1, r0[i]); x1 ^= x0; }
  x0 += ks2; x1 += ks0 + 5u;
}

struct Perm25 { int p[25]; };

static Perm25 compute_perm25() {
  uint32_t sk0 = 0u, sk1 = 1u;
  threefry2x32_block(0u, 42u, sk0, sk1);
  uint32_t bits[128];
  for (int i = 0; i < 128; ++i) {
    uint32_t x0 = 0u, x1 = (uint32_t)i;
    threefry2x32_block(sk0, sk1, x0, x1);
    bits[i] = x0 ^ x1;
  }
  int idxs[128];
  for (int i = 0; i < 128; ++i) idxs[i] = i;
  std::stable_sort(idxs, idxs + 128,
                   [&](int a, int b) { return bits[a] < bits[b]; });
  Perm25 out;
  for (int j = 0; j < 25; ++j) out.p[j] = idxs[j];
  return out;
}

#define NS 25
#define MAX_DEG 128
#define TMP_STRIDE 32       // compacted row padded to 128 B (aligned lines)

// clang native vector — __builtin_nontemporal_store requires this, not
// HIP's int4 class type.
typedef int iv4 __attribute__((ext_vector_type(4)));

// ---------------------------------------------------------------------------
// Kernel A: dedupe pass, 512 threads / 64 rows per block, ONE barrier.
// Each adjacency row is read from HBM exactly once (vs 2.62x average in a
// direct gather); its 25 permuted columns are compacted into tmp[node][0..24]
// (row padded to 128 B). 51.2 MB read + 12.8 MB write instead of 134 MB read.
// ---------------------------------------------------------------------------
#define A_ROWS 64
#define A_LDS_STRIDE 132    // 128+4 pad; 132*4=528 B keeps int4 alignment

__global__ __launch_bounds__(512)
void compact_rows_kernel(const int* __restrict__ adj,
                         int* __restrict__ tmp,
                         Perm25 perm, int n_nodes) {
  __shared__ int s_rows[A_ROWS * A_LDS_STRIDE];  // ~33.8 KB -> 4 blocks/CU
  __shared__ int s_perm[NS];

  const int tid = threadIdx.x;
  const int row0 = blockIdx.x * A_ROWS;
  if (tid < NS) s_perm[tid] = perm.p[tid];   // covered by the staging barrier

  // Stage 64 full rows, coalesced: 64 rows x 32 int4 chunks = 2048 chunks,
  // 512 threads x 4 iterations; consecutive tid -> consecutive chunks.
#pragma unroll
  for (int it = 0; it < 4; ++it) {
    const int idx = it * 512 + tid;
    const int r = idx >> 5;
    const int c = idx & 31;
    const int node = row0 + r;
    if (node < n_nodes) {
      const int4 v =
          *reinterpret_cast<const int4*>(adj + (size_t)node * MAX_DEG + c * 4);
      *reinterpret_cast<int4*>(&s_rows[r * A_LDS_STRIDE + c * 4]) = v;
    }
  }
  __syncthreads();

  // Gather 25 perm columns per row, pad to 32, write coalesced 128 B rows.
  // 64 rows x 8 int4 chunks = 512 threads exactly (all lanes active).
  const int r = tid >> 3;
  const int q = tid & 7;
  const int node = row0 + r;
  if (node < n_nodes) {
    iv4 v;
#pragma unroll
    for (int e = 0; e < 4; ++e) {
      const int j = q * 4 + e;
      v[e] = (j < NS) ? s_rows[r * A_LDS_STRIDE + s_perm[j]] : 0;
    }
    *reinterpret_cast<iv4*>(tmp + (size_t)node * TMP_STRIDE + q * 4) = v;
  }
}

// ---------------------------------------------------------------------------
// Kernel B: 512 threads / 64 rows per block, ONE barrier. Stage 64 compacted
// rows tmp[ids[...]] (128 B each, aligned single-line reads, IC-hot from
// kernel A), then write both outputs coalesced with non-temporal stores
// (outputs are never re-read).
// ---------------------------------------------------------------------------
#define B_ROWS 64
#define B_STRIDE 36         // 36*4=144 B: int4-aligned, banks rotate 4/row
#define B_ELEMS (B_ROWS * NS)   // 1600 outputs/block/output-array

__global__ __launch_bounds__(512)
void scatter_out_kernel(const int* __restrict__ tmp,
                        const int* __restrict__ ids,
                        int* __restrict__ out, int batch) {
  __shared__ int s_tmp[B_ROWS * B_STRIDE];  // 9.2 KB

  const int tid = threadIdx.x;
  const int row0 = blockIdx.x * B_ROWS;

  // Stage: thread t -> row r=t>>3, int4 chunk q=t&7 (one 128 B line per row,
  // 8 lanes per line). node fetched directly (L1-broadcast of ids words).
  {
    const int r = tid >> 3;
    const int q = tid & 7;
    const int gr = row0 + r;
    const int node = (gr < batch) ? ids[gr] : 0;
    const int4 v = *reinterpret_cast<const int4*>(
        tmp + (size_t)node * TMP_STRIDE + q * 4);
    *reinterpret_cast<int4*>(&s_tmp[r * B_STRIDE + q * 4]) = v;
  }
  __syncthreads();

  // 1600 outputs = 400 int4 NT stores per output array.
  if (tid < B_ELEMS / 4) {
    iv4 v;
#pragma unroll
    for (int e = 0; e < 4; ++e) {
      const int li = tid * 4 + e;
      const unsigned r = (unsigned)li / NS;   // magic-mul div
      const int j = li - (int)r * NS;
      v[e] = s_tmp[r * B_STRIDE + j];
    }
    const size_t base = (size_t)blockIdx.x * B_ELEMS + (size_t)tid * 4;
    const size_t total = (size_t)batch * NS;
    if (base + 4 <= total) {
      __builtin_nontemporal_store(v, reinterpret_cast<iv4*>(out + base));
      __builtin_nontemporal_store(v,
                                  reinterpret_cast<iv4*>(out + total + base));
    }
  }
}

// ---------------------------------------------------------------------------
// Fallback (round-2/3 verified shape): direct gather, used only if ws too
// small for tmp.
// ---------------------------------------------------------------------------
#define F_ROWS 32
#define F_ELEMS (F_ROWS * NS)

__global__ __launch_bounds__(256)
void direct_sampler_kernel(const int* __restrict__ adj,
                           const int* __restrict__ ids,
                           int* __restrict__ out,
                           Perm25 perm, int batch) {
  __shared__ int s_rows[F_ROWS * A_LDS_STRIDE];
  __shared__ int s_ids[F_ROWS];
  __shared__ int s_perm[NS];

  const int tid = threadIdx.x;
  const int row0 = blockIdx.x * F_ROWS;
  if (tid < F_ROWS) {
    const int gr = row0 + tid;
    s_ids[tid] = (gr < batch) ? ids[gr] : 0;
  }
  if (tid < NS) s_perm[tid] = perm.p[tid];
  __syncthreads();
#pragma unroll
  for (int it = 0; it < 4; ++it) {
    const int r = it * 8 + (tid >> 5);
    const int c = tid & 31;
    const int node = s_ids[r];
    const int4 v =
        *reinterpret_cast<const int4*>(adj + (size_t)node * MAX_DEG + c * 4);
    *reinterpret_cast<int4*>(&s_rows[r * A_LDS_STRIDE + c * 4]) = v;
  }
  __syncthreads();
  if (tid < F_ELEMS / 4) {
    iv4 v;
#pragma unroll
    for (int e = 0; e < 4; ++e) {
      const int li = tid * 4 + e;
      const unsigned r = (unsigned)li / NS;
      const int j = li - (int)r * NS;
      v[e] = s_rows[r * A_LDS_STRIDE + s_perm[j]];
    }
    const size_t base = (size_t)blockIdx.x * F_ELEMS + (size_t)tid * 4;
    const size_t total = (size_t)batch * NS;
    if (base + 4 <= total) {
      __builtin_nontemporal_store(v, reinterpret_cast<iv4*>(out + base));
      __builtin_nontemporal_store(v,
                                  reinterpret_cast<iv4*>(out + total + base));
    }
  }
}

extern "C" void kernel_launch(void* const* d_in, const int* in_sizes, int n_in,
                              void* d_out, int out_size, void* d_ws, size_t ws_size,
                              hipStream_t stream) {
  const int* adj = (const int*)d_in[0];   // (100000, 128) int32
  const int* ids = (const int*)d_in[1];   // (262144,)    int32

  const int n_nodes = in_sizes[0] / MAX_DEG;  // 100000
  const int batch = in_sizes[1];              // 262144

  const Perm25 perm = compute_perm25();       // host arithmetic, deterministic

  const size_t tmp_bytes = (size_t)n_nodes * TMP_STRIDE * sizeof(int);

  if (ws_size >= tmp_bytes) {
    int* tmp = (int*)d_ws;
    const int gridA = (n_nodes + A_ROWS - 1) / A_ROWS;  // 1563
    const int gridB = (batch + B_ROWS - 1) / B_ROWS;    // 4096
    compact_rows_kernel<<<gridA, 512, 0, stream>>>(adj, tmp, perm, n_nodes);
    scatter_out_kernel<<<gridB, 512, 0, stream>>>(tmp, ids, (int*)d_out, batch);
  } else {
    const int gridF = (batch + F_ROWS - 1) / F_ROWS;
    direct_sampler_kernel<<<gridF, 256, 0, stream>>>(adj, ids, (int*)d_out,
                                                     perm, batch);
  }
}

// Round 7
// 28.370 us; speedup vs baseline: 1.0130x; 1.0130x over previous
//
#include <hip/hip_runtime.h>
#include <algorithm>
#include <cstdint>

// ---------------------------------------------------------------------------
// Host-side reproduction of jax.random.permutation(jax.random.key(42), 128)
// under jax_threefry_partitionable=True (default since JAX 0.4.36):
//   subkey = threefry_block(key=(0,42), x0=0, x1=1) (both output words)
//   bits[i] = x0out ^ x1out of block(subkey, x0=0, x1=i), i in [0,128)
//   perm = stable argsort(bits); use perm[0:25]
// (Verified passing on this harness, rounds 2-6.)
// ---------------------------------------------------------------------------

static inline void threefry2x32_block(uint32_t k0, uint32_t k1,
                                      uint32_t& x0, uint32_t& x1) {
  auto rotl = [](uint32_t v, int d) { return (v << d) | (v >> (32 - d)); };
  const int r0[4] = {13, 15, 26, 6};
  const int r1[4] = {17, 29, 16, 24};
  const uint32_t ks0 = k0, ks1 = k1, ks2 = k0 ^ k1 ^ 0x1BD11BDAu;
  x0 += ks0; x1 += ks1;
  for (int i = 0; i < 4; ++i) { x0 += x1; x1 = rotl(x1, r0[i]); x1 ^= x0; }
  x0 += ks1; x1 += ks2 + 1u;
  for (int i = 0; i < 4; ++i) { x0 += x1; x1 = rotl(x1, r1[i]); x1 ^= x0; }
  x0 += ks2; x1 += ks0 + 2u;
  for (int i = 0; i < 4; ++i) { x0 += x1; x1 = rotl(x1, r0[i]); x1 ^= x0; }
  x0 += ks0; x1 += ks1 + 3u;
  for (int i = 0; i < 4; ++i) { x0 += x1; x1 = rotl(x1, r1[i]); x1 ^= x0; }
  x0 += ks1; x1 += ks2 + 4u;
  for (int i = 0; i < 4; ++i) { x0 += x1; x1 = rotl(x1, r0[i]); x1 ^= x0; }
  x0 += ks2; x1 += ks0 + 5u;
}

struct Perm25 { int p[25]; };

static Perm25 compute_perm25() {
  uint32_t sk0 = 0u, sk1 = 1u;
  threefry2x32_block(0u, 42u, sk0, sk1);
  uint32_t bits[128];
  for (int i = 0; i < 128; ++i) {
    uint32_t x0 = 0u, x1 = (uint32_t)i;
    threefry2x32_block(sk0, sk1, x0, x1);
    bits[i] = x0 ^ x1;
  }
  int idxs[128];
  for (int i = 0; i < 128; ++i) idxs[i] = i;
  std::stable_sort(idxs, idxs + 128,
                   [&](int a, int b) { return bits[a] < bits[b]; });
  Perm25 out;
  for (int j = 0; j < 25; ++j) out.p[j] = idxs[j];
  return out;
}

#define NS 25
#define MAX_DEG 128
#define BITS 17             // node ids < 100000 < 2^17
#define VMASK 0x1FFFFu
#define TMP_WORDS 16        // packed row: 25*17=425 bits -> 64 B (16 dwords)

// clang native vector — __builtin_nontemporal_store requires this, not
// HIP's int4 class type.
typedef int iv4 __attribute__((ext_vector_type(4)));

// ---------------------------------------------------------------------------
// Kernel A: dedupe + pack. Each adjacency row read from HBM exactly once;
// its 25 permuted columns are packed 17-bit-tight into a 64 B tmp row.
// HBM: 51.2 MB read + 6.4 MB write (was 12.8 MB unpacked).
// ---------------------------------------------------------------------------
#define A_ROWS 64
#define A_LDS_STRIDE 132    // 128+4 pad; keeps int4 alignment

__global__ __launch_bounds__(512)
void compact_rows_kernel(const int* __restrict__ adj,
                         uint32_t* __restrict__ tmp,
                         Perm25 perm, int n_nodes) {
  __shared__ int s_rows[A_ROWS * A_LDS_STRIDE];  // ~33.8 KB
  __shared__ int s_perm[NS];

  const int tid = threadIdx.x;
  const int row0 = blockIdx.x * A_ROWS;
  if (tid < NS) s_perm[tid] = perm.p[tid];   // covered by the staging barrier

  // Stage 64 full rows, coalesced: 2048 int4 chunks over 512 threads x 4.
#pragma unroll
  for (int it = 0; it < 4; ++it) {
    const int idx = it * 512 + tid;
    const int r = idx >> 5;
    const int c = idx & 31;
    const int node = row0 + r;
    if (node < n_nodes) {
      const int4 v =
          *reinterpret_cast<const int4*>(adj + (size_t)node * MAX_DEG + c * 4);
      *reinterpret_cast<int4*>(&s_rows[r * A_LDS_STRIDE + c * 4]) = v;
    }
  }
  __syncthreads();

  // Pack: thread t -> row r=t>>3 handles dwords w=2q, 2q+1 (q=t&7).
  // Dword w holds packed bits [32w, 32w+32); value j occupies [17j, 17j+17).
  const int r = tid >> 3;
  const int q = tid & 7;
  const int node = row0 + r;
  if (node < n_nodes) {
    uint32_t d[2];
#pragma unroll
    for (int k = 0; k < 2; ++k) {
      const int w = 2 * q + k;
      uint32_t acc = 0;
      const int jlo = (32 * w) / BITS;
      int jhi = (32 * w + 31) / BITS;
      if (jhi > NS - 1) jhi = NS - 1;
      for (int j = jlo; j <= jhi; ++j) {
        const uint32_t val =
            (uint32_t)s_rows[r * A_LDS_STRIDE + s_perm[j]] & VMASK;
        const int sh = 32 * w - BITS * j;
        acc |= (sh >= 0) ? (val >> sh) : (val << (-sh));
      }
      d[k] = acc;
    }
    // 8 B per thread, 8 threads/row -> 64 B contiguous, coalesced.
    *reinterpret_cast<uint2*>(tmp + (size_t)node * TMP_WORDS + 2 * q) =
        make_uint2(d[0], d[1]);
  }
}

// ---------------------------------------------------------------------------
// Kernel B: stage 64 packed rows tmp[ids[...]] (64 B each, single half-line
// aligned reads), unpack 17-bit fields, write both outputs coalesced with
// non-temporal stores (outputs never re-read; keep IC for tmp).
// ---------------------------------------------------------------------------
#define B_ROWS 64
#define B_STRIDE 18         // 16 + 2 pad dwords: 8B-aligned, banks rotate
#define B_ELEMS (B_ROWS * NS)   // 1600 outputs/block/output-array

__global__ __launch_bounds__(512)
void scatter_out_kernel(const uint32_t* __restrict__ tmp,
                        const int* __restrict__ ids,
                        int* __restrict__ out, int batch) {
  __shared__ uint32_t s_tmp[B_ROWS * B_STRIDE];  // 4.6 KB

  const int tid = threadIdx.x;
  const int row0 = blockIdx.x * B_ROWS;

  // Stage: thread t -> row r=t>>3, uint2 chunk c=t&7 (8 lanes x 8 B = one
  // 64 B row, contiguous). All 512 threads active, one chunk each.
  {
    const int r = tid >> 3;
    const int c = tid & 7;
    const int gr = row0 + r;
    const int node = (gr < batch) ? ids[gr] : 0;
    const uint2 v = *reinterpret_cast<const uint2*>(
        tmp + (size_t)node * TMP_WORDS + 2 * c);
    *reinterpret_cast<uint2*>(&s_tmp[r * B_STRIDE + 2 * c]) = v;
  }
  __syncthreads();

  // 1600 outputs = 400 int4 NT stores per output array.
  if (tid < B_ELEMS / 4) {
    iv4 v;
#pragma unroll
    for (int e = 0; e < 4; ++e) {
      const int li = tid * 4 + e;
      const unsigned r = (unsigned)li / NS;   // magic-mul div
      const int j = li - (int)r * NS;
      const int bit = BITS * j;
      const int w0 = bit >> 5;
      const int off = bit & 31;
      const uint64_t lo = s_tmp[r * B_STRIDE + w0];
      const uint64_t hi = s_tmp[r * B_STRIDE + w0 + 1];  // w0+1 <= 13 < 16
      v[e] = (int)((((hi << 32) | lo) >> off) & VMASK);
    }
    const size_t base = (size_t)blockIdx.x * B_ELEMS + (size_t)tid * 4;
    const size_t total = (size_t)batch * NS;
    if (base + 4 <= total) {
      __builtin_nontemporal_store(v, reinterpret_cast<iv4*>(out + base));
      __builtin_nontemporal_store(v,
                                  reinterpret_cast<iv4*>(out + total + base));
    }
  }
}

// ---------------------------------------------------------------------------
// Fallback (round-2/3 verified shape): direct gather, used only if ws too
// small for tmp (6.4 MB).
// ---------------------------------------------------------------------------
#define F_ROWS 32
#define F_ELEMS (F_ROWS * NS)

__global__ __launch_bounds__(256)
void direct_sampler_kernel(const int* __restrict__ adj,
                           const int* __restrict__ ids,
                           int* __restrict__ out,
                           Perm25 perm, int batch) {
  __shared__ int s_rows[F_ROWS * A_LDS_STRIDE];
  __shared__ int s_ids[F_ROWS];
  __shared__ int s_perm[NS];

  const int tid = threadIdx.x;
  const int row0 = blockIdx.x * F_ROWS;
  if (tid < F_ROWS) {
    const int gr = row0 + tid;
    s_ids[tid] = (gr < batch) ? ids[gr] : 0;
  }
  if (tid < NS) s_perm[tid] = perm.p[tid];
  __syncthreads();
#pragma unroll
  for (int it = 0; it < 4; ++it) {
    const int r = it * 8 + (tid >> 5);
    const int c = tid & 31;
    const int node = s_ids[r];
    const int4 v =
        *reinterpret_cast<const int4*>(adj + (size_t)node * MAX_DEG + c * 4);
    *reinterpret_cast<int4*>(&s_rows[r * A_LDS_STRIDE + c * 4]) = v;
  }
  __syncthreads();
  if (tid < F_ELEMS / 4) {
    iv4 v;
#pragma unroll
    for (int e = 0; e < 4; ++e) {
      const int li = tid * 4 + e;
      const unsigned r = (unsigned)li / NS;
      const int j = li - (int)r * NS;
      v[e] = s_rows[r * A_LDS_STRIDE + s_perm[j]];
    }
    const size_t base = (size_t)blockIdx.x * F_ELEMS + (size_t)tid * 4;
    const size_t total = (size_t)batch * NS;
    if (base + 4 <= total) {
      __builtin_nontemporal_store(v, reinterpret_cast<iv4*>(out + base));
      __builtin_nontemporal_store(v,
                                  reinterpret_cast<iv4*>(out + total + base));
    }
  }
}

extern "C" void kernel_launch(void* const* d_in, const int* in_sizes, int n_in,
                              void* d_out, int out_size, void* d_ws, size_t ws_size,
                              hipStream_t stream) {
  const int* adj = (const int*)d_in[0];   // (100000, 128) int32
  const int* ids = (const int*)d_in[1];   // (262144,)    int32

  const int n_nodes = in_sizes[0] / MAX_DEG;  // 100000
  const int batch = in_sizes[1];              // 262144

  const Perm25 perm = compute_perm25();       // host arithmetic, deterministic

  const size_t tmp_bytes = (size_t)n_nodes * TMP_WORDS * sizeof(uint32_t);

  if (ws_size >= tmp_bytes) {
    uint32_t* tmp = (uint32_t*)d_ws;
    const int gridA = (n_nodes + A_ROWS - 1) / A_ROWS;  // 1563
    const int gridB = (batch + B_ROWS - 1) / B_ROWS;    // 4096
    compact_rows_kernel<<<gridA, 512, 0, stream>>>(adj, tmp, perm, n_nodes);
    scatter_out_kernel<<<gridB, 512, 0, stream>>>(tmp, ids, (int*)d_out, batch);
  } else {
    const int gridF = (batch + F_ROWS - 1) / F_ROWS;
    direct_sampler_kernel<<<gridF, 256, 0, stream>>>(adj, ids, (int*)d_out,
                                                     perm, batch);
  }
}